// Round 11
// baseline (165.457 us; speedup 1.0000x reference)
//
#include <hip/hip_runtime.h>
#include <hip/hip_bf16.h>

typedef __attribute__((ext_vector_type(4))) float f32x4;
typedef __attribute__((ext_vector_type(8))) short bf16x8;
typedef __attribute__((ext_vector_type(4))) int i32x4;

#define SEQ 1024
#define HIDV 768
#define NH 12
#define HD 64
#define QBLK 64
#define SPITCH 1032  /* Sbuf row pitch in bf16 elems: 1024 + 8 pad (bank spread) */
#define ATTN_LDS ((64 * SPITCH + 2 * 64 * 72) * 2)  /* 150528 B */

static __device__ __forceinline__ unsigned short f2b(float f) {
  unsigned u = __builtin_bit_cast(unsigned, f);
  u = (u + 0x7fffu + ((u >> 16) & 1u)) >> 16;
  return (unsigned short)u;
}
static __device__ __forceinline__ float b2f(unsigned short u) {
  return __builtin_bit_cast(float, (unsigned)u << 16);
}

static __device__ __forceinline__ void gl16(const unsigned short* g, unsigned short* l) {
  __builtin_amdgcn_global_load_lds(
      (const __attribute__((address_space(1))) unsigned int*)g,
      (__attribute__((address_space(3))) unsigned int*)l, 16, 0, 0);
}

// barrier that waits ONLY on LDS ops (keeps global stores/loads in flight)
static __device__ __forceinline__ void bar_lgkm() {
  asm volatile("s_waitcnt lgkmcnt(0)" ::: "memory");
  __builtin_amdgcn_sched_barrier(0);
  __builtin_amdgcn_s_barrier();
  __builtin_amdgcn_sched_barrier(0);
}
// rendezvous-only barrier
static __device__ __forceinline__ void bar_only() {
  __builtin_amdgcn_sched_barrier(0);
  __builtin_amdgcn_s_barrier();
  __builtin_amdgcn_sched_barrier(0);
}

// ---------- convert f32 inputs -> bf16 (X, Wq, Wk, Wv, Wo contiguous in ws) ----------
__global__ __launch_bounds__(256) void convert_all(
    const float* __restrict__ X, const float* __restrict__ Wq,
    const float* __restrict__ Wk, const float* __restrict__ Wv,
    const float* __restrict__ Wo, unsigned short* __restrict__ dst) {
  long i = (long)blockIdx.x * 256 + threadIdx.x;
  const long N4 = (3145728L + 4 * 589824L) / 4;
  if (i >= N4) return;
  long e = i * 4;
  const float* src; long off;
  if (e < 3145728L)      { src = X;  off = e; }
  else if (e < 3735552L) { src = Wq; off = e - 3145728L; }
  else if (e < 4325376L) { src = Wk; off = e - 3735552L; }
  else if (e < 4915200L) { src = Wv; off = e - 4325376L; }
  else                   { src = Wo; off = e - 4915200L; }
  const float4 v = *reinterpret_cast<const float4*>(src + off);
  ushort4 o;
  o.x = f2b(v.x); o.y = f2b(v.y); o.z = f2b(v.z); o.w = f2b(v.w);
  *reinterpret_cast<ushort4*>(dst + e) = o;
}

// ---------- fused QKV GEMM: T3-min pipeline (r6 version, best measured) ----------
__global__ __launch_bounds__(256) void qkv_gemm(
    const unsigned short* __restrict__ Xb,
    const unsigned short* __restrict__ Wqb, const unsigned short* __restrict__ Wkb,
    const unsigned short* __restrict__ Wvb,
    const float* __restrict__ bq, const float* __restrict__ bk, const float* __restrict__ bv,
    unsigned short* __restrict__ Qh, unsigned short* __restrict__ Kh,
    unsigned short* __restrict__ VT) {
  __shared__ __align__(16) unsigned short la[2][128 * 32];
  __shared__ __align__(16) unsigned short lb[2][128 * 32];
  const int z = blockIdx.z;
  const unsigned short* Wb = (z == 0) ? Wqb : (z == 1) ? Wkb : Wvb;
  const float* bias = (z == 0) ? bq : (z == 1) ? bk : bv;
  const int m0 = blockIdx.x * 128, n0 = blockIdx.y * 128;
  const int tid = threadIdx.x;
  const int wave = tid >> 6, lane = tid & 63, g = lane >> 4, c = lane & 15;
  const int wr = (wave >> 1) * 64, wc = (wave & 1) * 64;

  const int sr = wave * 16 + (lane >> 2);
  const int scol = (lane & 3) * 8;
  const unsigned short* Ag = &Xb[(size_t)(m0 + sr) * HIDV + scol];
  const unsigned short* Bg = &Wb[(size_t)(n0 + sr) * HIDV + scol];

  gl16(Ag, &la[0][(wave * 16) * 32]);
  gl16(Ag + (size_t)64 * HIDV, &la[0][(64 + wave * 16) * 32]);
  gl16(Bg, &lb[0][(wave * 16) * 32]);
  gl16(Bg + (size_t)64 * HIDV, &lb[0][(64 + wave * 16) * 32]);
  __syncthreads();

  f32x4 acc[4][4] = {};
  for (int t = 0; t < 24; t++) {
    const int cur = t & 1;
    if (t < 23) {
      const int kt = (t + 1) * 32;
      gl16(Ag + kt, &la[cur ^ 1][(wave * 16) * 32]);
      gl16(Ag + (size_t)64 * HIDV + kt, &la[cur ^ 1][(64 + wave * 16) * 32]);
      gl16(Bg + kt, &lb[cur ^ 1][(wave * 16) * 32]);
      gl16(Bg + (size_t)64 * HIDV + kt, &lb[cur ^ 1][(64 + wave * 16) * 32]);
    }
    bf16x8 af[4], bfr[4];
#pragma unroll
    for (int m = 0; m < 4; m++)
      af[m] = *reinterpret_cast<bf16x8*>(&la[cur][(wr + m * 16 + c) * 32 + g * 8]);
#pragma unroll
    for (int n = 0; n < 4; n++)
      bfr[n] = *reinterpret_cast<bf16x8*>(&lb[cur][(wc + n * 16 + c) * 32 + g * 8]);
#pragma unroll
    for (int m = 0; m < 4; m++)
#pragma unroll
      for (int n = 0; n < 4; n++)
        acc[m][n] = __builtin_amdgcn_mfma_f32_16x16x32_bf16(af[m], bfr[n], acc[m][n], 0, 0, 0);
    __syncthreads();
  }
  float bv4[4];
#pragma unroll
  for (int n = 0; n < 4; n++) bv4[n] = bias[n0 + wc + n * 16 + c];
  if (z < 2) {
    unsigned short* dst = (z == 0) ? Qh : Kh;
#pragma unroll
    for (int m = 0; m < 4; m++) {
      int rb_ = m0 + wr + m * 16 + g * 4;
#pragma unroll
      for (int n = 0; n < 4; n++) {
        int col = n0 + wc + n * 16 + c;
        int h = col >> 6, d = col & 63;
#pragma unroll
        for (int r = 0; r < 4; r++) {
          int row = rb_ + r;
          int b = row >> 10, s = row & 1023;
          dst[((size_t)(b * NH + h) * SEQ + s) * HD + d] = f2b(acc[m][n][r] + bv4[n]);
        }
      }
    }
  } else {
#pragma unroll
    for (int m = 0; m < 4; m++) {
      int rb_ = m0 + wr + m * 16 + g * 4;
      int b = rb_ >> 10, s = rb_ & 1023;
#pragma unroll
      for (int n = 0; n < 4; n++) {
        int col = n0 + wc + n * 16 + c;
        int h = col >> 6, d = col & 63;
        ushort4 o;
        o.x = f2b(acc[m][n][0] + bv4[n]);
        o.y = f2b(acc[m][n][1] + bv4[n]);
        o.z = f2b(acc[m][n][2] + bv4[n]);
        o.w = f2b(acc[m][n][3] + bv4[n]);
        *reinterpret_cast<ushort4*>(&VT[((size_t)(b * NH + h) * HD + d) * SEQ + s]) = o;
      }
    }
  }
}

// ---------- fused attention: SINGLE sweep, deferred normalization, Sbuf in LDS ----------
// QK^T computed ONCE; p~=exp2(s*c) stored bf16 in Sbuf[64][1032]; PV runs on
// unnormalized p~ (scale acc by 1/sum at end); probs written in a final pure
// streaming phase from Sbuf * linv. Dynamic LDS = 150528 B -> 1 block/CU.
#define EXPC 0.18033688f /* 0.125 * log2(e) */
__global__ __launch_bounds__(256) void attn_fused(
    const unsigned short* __restrict__ Qh, const unsigned short* __restrict__ Kh,
    const unsigned short* __restrict__ VT,
    float* __restrict__ probs, unsigned short* __restrict__ CTX) {
  extern __shared__ __align__(16) unsigned short smem[];
  unsigned short* Sbuf = smem;                 // [64][SPITCH]
  unsigned short* ldsk = smem + 64 * SPITCH;   // [64][72]
  unsigned short* ldsv = ldsk + 64 * 72;       // [64][72]
  float* linvf = (float*)ldsv;                 // reused after sweep (64 floats)

  const int lin = blockIdx.x;
  const int swz = (lin & 7) * 96 + (lin >> 3);
  const int bh = swz >> 4, rb = (swz & 15) * QBLK;
  const int b = bh / NH, h = bh - b * NH;
  const unsigned short* Qp = Qh + (size_t)bh * SEQ * HD;
  const unsigned short* Kp = Kh + (size_t)bh * SEQ * HD;
  const unsigned short* Vp = VT + (size_t)bh * HD * SEQ;
  float* P = probs + (size_t)bh * SEQ * SEQ;
  const int tid = threadIdx.x, wave = tid >> 6, lane = tid & 63, g = lane >> 4, c = lane & 15;
  const int wrow = wave * 16;
  const int str = tid >> 3;
  const int stc = (tid & 7) * 8;

  bf16x8 aq[2];
#pragma unroll
  for (int ks = 0; ks < 2; ks++)
    aq[ks] = *reinterpret_cast<const bf16x8*>(&Qp[(size_t)(rb + wrow + c) * HD + ks * 32 + g * 8]);

  i32x4 kr0, kr1, vr0, vr1;
  // prologue: stage tile 0 K+V
  kr0 = *reinterpret_cast<const i32x4*>(&Kp[(size_t)str * HD + stc]);
  kr1 = *reinterpret_cast<const i32x4*>(&Kp[(size_t)(str + 32) * HD + stc]);
  vr0 = *reinterpret_cast<const i32x4*>(&Vp[(size_t)str * SEQ + stc]);
  vr1 = *reinterpret_cast<const i32x4*>(&Vp[(size_t)(str + 32) * SEQ + stc]);
  *reinterpret_cast<i32x4*>(&ldsk[str * 72 + stc]) = kr0;
  *reinterpret_cast<i32x4*>(&ldsk[(str + 32) * 72 + stc]) = kr1;
  *reinterpret_cast<i32x4*>(&ldsv[str * 72 + stc]) = vr0;
  *reinterpret_cast<i32x4*>(&ldsv[(str + 32) * 72 + stc]) = vr1;
  bar_lgkm();

  float lsum = 0.f;
  f32x4 acc[4] = {};
  for (int ct = 0; ct < 16; ct++) {
    if (ct < 15) {  // prefetch next tile into regs (latency hidden under compute)
      kr0 = *reinterpret_cast<const i32x4*>(&Kp[(size_t)((ct + 1) * 64 + str) * HD + stc]);
      kr1 = *reinterpret_cast<const i32x4*>(&Kp[(size_t)((ct + 1) * 64 + str + 32) * HD + stc]);
      vr0 = *reinterpret_cast<const i32x4*>(&Vp[(size_t)str * SEQ + (ct + 1) * 64 + stc]);
      vr1 = *reinterpret_cast<const i32x4*>(&Vp[(size_t)(str + 32) * SEQ + (ct + 1) * 64 + stc]);
    }
    // QK^T (swapped): lane holds s for q=wrow+c, k=ct*64+kb*16+g*4+r
    f32x4 sreg[4] = {};
    __builtin_amdgcn_s_setprio(1);
#pragma unroll
    for (int ks = 0; ks < 2; ks++) {
      bf16x8 kf[4];
#pragma unroll
      for (int kb = 0; kb < 4; kb++)
        kf[kb] = *reinterpret_cast<bf16x8*>(&ldsk[(kb * 16 + c) * 72 + ks * 32 + g * 8]);
#pragma unroll
      for (int kb = 0; kb < 4; kb++)
        sreg[kb] = __builtin_amdgcn_mfma_f32_16x16x32_bf16(kf[kb], aq[ks], sreg[kb], 0, 0, 0);
    }
    __builtin_amdgcn_s_setprio(0);
    // p~ = exp2(s*EXPC); accumulate lsum; stash bf16 p~ into Sbuf (per-wave rows)
    {
      unsigned short* srow = &Sbuf[(wrow + c) * SPITCH + ct * 64];
#pragma unroll
      for (int kb = 0; kb < 4; kb++) {
        f32x4 p;
#pragma unroll
        for (int r = 0; r < 4; r++) {
          p[r] = __builtin_amdgcn_exp2f(sreg[kb][r] * EXPC);
          lsum += p[r];
        }
        uint2 pk;
        pk.x = (unsigned)f2b(p[0]) | ((unsigned)f2b(p[1]) << 16);
        pk.y = (unsigned)f2b(p[2]) | ((unsigned)f2b(p[3]) << 16);
        *reinterpret_cast<uint2*>(&srow[kb * 16 + g * 4]) = pk;
      }
    }
    // PV with unnormalized p~ (A-fragment straight from Sbuf, within-wave rows)
    __builtin_amdgcn_s_setprio(1);
#pragma unroll
    for (int ks = 0; ks < 2; ks++) {
      bf16x8 pa, vf[4];
      pa = *reinterpret_cast<bf16x8*>(&Sbuf[(wrow + c) * SPITCH + ct * 64 + ks * 32 + g * 8]);
#pragma unroll
      for (int db = 0; db < 4; db++)
        vf[db] = *reinterpret_cast<bf16x8*>(&ldsv[(db * 16 + c) * 72 + ks * 32 + g * 8]);
#pragma unroll
      for (int db = 0; db < 4; db++)
        acc[db] = __builtin_amdgcn_mfma_f32_16x16x32_bf16(pa, vf[db], acc[db], 0, 0, 0);
    }
    __builtin_amdgcn_s_setprio(0);
    if (ct < 15) {
      bar_only();  // all waves done reading ldsk/ldsv of this tile
      *reinterpret_cast<i32x4*>(&ldsk[str * 72 + stc]) = kr0;
      *reinterpret_cast<i32x4*>(&ldsk[(str + 32) * 72 + stc]) = kr1;
      *reinterpret_cast<i32x4*>(&ldsv[str * 72 + stc]) = vr0;
      *reinterpret_cast<i32x4*>(&ldsv[(str + 32) * 72 + stc]) = vr1;
      bar_lgkm();  // next tile staged & visible
    }
  }

  // ---- normalization scalars ----
  float s = lsum;
  s += __shfl_xor(s, 16);
  s += __shfl_xor(s, 32);
  const float linv = 1.f / s;
  bar_only();  // all K/V/Sbuf tile reads complete before ldsv repurpose
  if (lane < 16) linvf[wrow + lane] = linv;  // q = wrow+lane, written by g==0 lanes

  // ---- CTX: scale acc by per-row linv, bounce via ldsk, coalesced stores ----
  float lv[4];
#pragma unroll
  for (int r = 0; r < 4; r++) lv[r] = linvf[wrow + g * 4 + r];  // own-wave rows
#pragma unroll
  for (int db = 0; db < 4; db++)
#pragma unroll
    for (int r = 0; r < 4; r++)
      ldsk[(wrow + g * 4 + r) * 72 + db * 16 + c] = f2b(acc[db][r] * lv[r]);
  bar_lgkm();  // publish ctx bounce + linvf for cross-wave reads
  {
    const int q = tid >> 2, seg = (tid & 3) * 16;
    const unsigned short* src = &ldsk[q * 72 + seg];
    unsigned short* dst = &CTX[(size_t)(b * SEQ + rb + q) * HIDV + h * HD + seg];
    i32x4 t0 = *reinterpret_cast<const i32x4*>(&src[0]);
    i32x4 t1 = *reinterpret_cast<const i32x4*>(&src[8]);
    *reinterpret_cast<i32x4*>(&dst[0]) = t0;
    *reinterpret_cast<i32x4*>(&dst[8]) = t1;
  }

  // ---- probs phase: pure streaming Sbuf*linv -> f32, fully coalesced ----
  // lane tid covers cols tid*4..tid*4+3 of each row: 16B/lane, 4KB/row.
#pragma unroll 4
  for (int r = 0; r < 64; r++) {
    const float lr = linvf[r];
    uint2 pk = *reinterpret_cast<const uint2*>(&Sbuf[r * SPITCH + tid * 4]);
    float4 o;
    o.x = b2f((unsigned short)(pk.x & 0xffff)) * lr;
    o.y = b2f((unsigned short)(pk.x >> 16)) * lr;
    o.z = b2f((unsigned short)(pk.y & 0xffff)) * lr;
    o.w = b2f((unsigned short)(pk.y >> 16)) * lr;
    *reinterpret_cast<float4*>(&P[(size_t)(rb + r) * SEQ + tid * 4]) = o;
  }
}

// ---------- output projection: 64x128 tile (384 blocks), T3-min pipeline ----------
__global__ __launch_bounds__(256) void proj_gemm(
    const unsigned short* __restrict__ Ab, const unsigned short* __restrict__ Wb,
    const float* __restrict__ bias, float* __restrict__ out) {
  __shared__ __align__(16) unsigned short la[2][64 * 32];
  __shared__ __align__(16) unsigned short lb[2][128 * 32];
  const int m0 = blockIdx.x * 64, n0 = blockIdx.y * 128;
  const int tid = threadIdx.x;
  const int wave = tid >> 6, lane = tid & 63, g = lane >> 4, c = lane & 15;
  const int wr = (wave >> 1) * 32, wc = (wave & 1) * 64;
  const int srb = wave * 16 + (lane >> 2);
  const int scol = (lane & 3) * 8;
  const unsigned short* Ag = &Ab[(size_t)(m0 + srb) * HIDV + scol];
  const unsigned short* Bg = &Wb[(size_t)(n0 + srb) * HIDV + scol];

#define PROJ_STAGE(buf, kt)                                               \
  do {                                                                    \
    gl16(Ag + (kt), &la[buf][(wave * 16) * 32]);                          \
    gl16(Bg + (kt), &lb[buf][(wave * 16) * 32]);                          \
    gl16(Bg + (size_t)64 * HIDV + (kt), &lb[buf][(64 + wave * 16) * 32]); \
  } while (0)

  PROJ_STAGE(0, 0);
  __syncthreads();

  f32x4 acc[2][4] = {};
  for (int t = 0; t < 24; t++) {
    const int cur = t & 1;
    if (t < 23) PROJ_STAGE(cur ^ 1, (t + 1) * 32);
    bf16x8 af[2], bfr[4];
#pragma unroll
    for (int m = 0; m < 2; m++)
      af[m] = *reinterpret_cast<bf16x8*>(&la[cur][(wr + m * 16 + c) * 32 + g * 8]);
#pragma unroll
    for (int n = 0; n < 4; n++)
      bfr[n] = *reinterpret_cast<bf16x8*>(&lb[cur][(wc + n * 16 + c) * 32 + g * 8]);
#pragma unroll
    for (int m = 0; m < 2; m++)
#pragma unroll
      for (int n = 0; n < 4; n++)
        acc[m][n] = __builtin_amdgcn_mfma_f32_16x16x32_bf16(af[m], bfr[n], acc[m][n], 0, 0, 0);
    __syncthreads();
  }
#undef PROJ_STAGE
  float bv4[4];
#pragma unroll
  for (int n = 0; n < 4; n++) bv4[n] = bias[n0 + wc + n * 16 + c];
#pragma unroll
  for (int m = 0; m < 2; m++) {
    int rb_ = m0 + wr + m * 16 + g * 4;
#pragma unroll
    for (int n = 0; n < 4; n++) {
      int col = n0 + wc + n * 16 + c;
#pragma unroll
      for (int r = 0; r < 4; r++)
        out[(size_t)(rb_ + r) * HIDV + col] = acc[m][n][r] + bv4[n];
    }
  }
}

extern "C" void kernel_launch(void* const* d_in, const int* in_sizes, int n_in,
                              void* d_out, int out_size, void* d_ws, size_t ws_size,
                              hipStream_t stream) {
  const float* X  = (const float*)d_in[0];
  const float* Wq = (const float*)d_in[1];
  const float* bq = (const float*)d_in[2];
  const float* Wk = (const float*)d_in[3];
  const float* bk = (const float*)d_in[4];
  const float* Wv = (const float*)d_in[5];
  const float* bv = (const float*)d_in[6];
  const float* Wo = (const float*)d_in[7];
  const float* bo = (const float*)d_in[8];
  float* out = (float*)d_out;
  float* probs = out + 3145728;  // output 1 region

  unsigned short* Xb  = (unsigned short*)d_ws;        // [4096,768]
  unsigned short* Wqb = Xb + 3145728;                 // [768,768]
  unsigned short* Wkb = Wqb + 589824;
  unsigned short* Wvb = Wkb + 589824;
  unsigned short* Wob = Wvb + 589824;
  unsigned short* Qh  = Wob + 589824;                 // [4,12,1024,64]
  unsigned short* Kh  = Qh + 3145728;
  unsigned short* VT  = Kh + 3145728;                 // [4,12,64,1024]
  unsigned short* CTX = VT + 3145728;                 // [4096,768]

  // allow >64KB dynamic LDS for attn (capture-safe host-side attribute)
  hipFuncSetAttribute(reinterpret_cast<const void*>(attn_fused),
                      hipFuncAttributeMaxDynamicSharedMemorySize, ATTN_LDS);

  convert_all<<<5376, 256, 0, stream>>>(X, Wq, Wk, Wv, Wo, Xb);
  qkv_gemm<<<dim3(32, 6, 3), 256, 0, stream>>>(Xb, Wqb, Wkb, Wvb, bq, bk, bv, Qh, Kh, VT);
  attn_fused<<<dim3(768), 256, ATTN_LDS, stream>>>(Qh, Kh, VT, probs, CTX);
  proj_gemm<<<dim3(64, 6), 256, 0, stream>>>(CTX, Wob, bo, out);
}

// Round 12
// 148.206 us; speedup vs baseline: 1.1164x; 1.1164x over previous
//
#include <hip/hip_runtime.h>
#include <hip/hip_bf16.h>

typedef __attribute__((ext_vector_type(4))) float f32x4;
typedef __attribute__((ext_vector_type(8))) short bf16x8;
typedef __attribute__((ext_vector_type(4))) int i32x4;

#define SEQ 1024
#define HIDV 768
#define NH 12
#define HD 64
#define QBLK 64

static __device__ __forceinline__ unsigned short f2b(float f) {
  unsigned u = __builtin_bit_cast(unsigned, f);
  u = (u + 0x7fffu + ((u >> 16) & 1u)) >> 16;
  return (unsigned short)u;
}
static __device__ __forceinline__ float b2f(unsigned short u) {
  return __builtin_bit_cast(float, (unsigned)u << 16);
}

static __device__ __forceinline__ void gl16(const unsigned short* g, unsigned short* l) {
  __builtin_amdgcn_global_load_lds(
      (const __attribute__((address_space(1))) unsigned int*)g,
      (__attribute__((address_space(3))) unsigned int*)l, 16, 0, 0);
}

// barrier that waits ONLY on LDS ops (keeps global stores/loads in flight)
static __device__ __forceinline__ void bar_lgkm() {
  asm volatile("s_waitcnt lgkmcnt(0)" ::: "memory");
  __builtin_amdgcn_sched_barrier(0);
  __builtin_amdgcn_s_barrier();
  __builtin_amdgcn_sched_barrier(0);
}

// ---------- convert f32 inputs -> bf16 (X, Wq, Wk, Wv, Wo contiguous in ws) ----------
__global__ __launch_bounds__(256) void convert_all(
    const float* __restrict__ X, const float* __restrict__ Wq,
    const float* __restrict__ Wk, const float* __restrict__ Wv,
    const float* __restrict__ Wo, unsigned short* __restrict__ dst) {
  long i = (long)blockIdx.x * 256 + threadIdx.x;
  const long N4 = (3145728L + 4 * 589824L) / 4;
  if (i >= N4) return;
  long e = i * 4;
  const float* src; long off;
  if (e < 3145728L)      { src = X;  off = e; }
  else if (e < 3735552L) { src = Wq; off = e - 3145728L; }
  else if (e < 4325376L) { src = Wk; off = e - 3735552L; }
  else if (e < 4915200L) { src = Wv; off = e - 4325376L; }
  else                   { src = Wo; off = e - 4915200L; }
  const float4 v = *reinterpret_cast<const float4*>(src + off);
  ushort4 o;
  o.x = f2b(v.x); o.y = f2b(v.y); o.z = f2b(v.z); o.w = f2b(v.w);
  *reinterpret_cast<ushort4*>(dst + e) = o;
}

// ---------- fused QKV GEMM: T3-min pipeline (r6/r10 version, best measured) ----------
__global__ __launch_bounds__(256) void qkv_gemm(
    const unsigned short* __restrict__ Xb,
    const unsigned short* __restrict__ Wqb, const unsigned short* __restrict__ Wkb,
    const unsigned short* __restrict__ Wvb,
    const float* __restrict__ bq, const float* __restrict__ bk, const float* __restrict__ bv,
    unsigned short* __restrict__ Qh, unsigned short* __restrict__ Kh,
    unsigned short* __restrict__ VT) {
  __shared__ __align__(16) unsigned short la[2][128 * 32];
  __shared__ __align__(16) unsigned short lb[2][128 * 32];
  const int z = blockIdx.z;
  const unsigned short* Wb = (z == 0) ? Wqb : (z == 1) ? Wkb : Wvb;
  const float* bias = (z == 0) ? bq : (z == 1) ? bk : bv;
  const int m0 = blockIdx.x * 128, n0 = blockIdx.y * 128;
  const int tid = threadIdx.x;
  const int wave = tid >> 6, lane = tid & 63, g = lane >> 4, c = lane & 15;
  const int wr = (wave >> 1) * 64, wc = (wave & 1) * 64;

  const int sr = wave * 16 + (lane >> 2);
  const int scol = (lane & 3) * 8;
  const unsigned short* Ag = &Xb[(size_t)(m0 + sr) * HIDV + scol];
  const unsigned short* Bg = &Wb[(size_t)(n0 + sr) * HIDV + scol];

  gl16(Ag, &la[0][(wave * 16) * 32]);
  gl16(Ag + (size_t)64 * HIDV, &la[0][(64 + wave * 16) * 32]);
  gl16(Bg, &lb[0][(wave * 16) * 32]);
  gl16(Bg + (size_t)64 * HIDV, &lb[0][(64 + wave * 16) * 32]);
  __syncthreads();

  f32x4 acc[4][4] = {};
  for (int t = 0; t < 24; t++) {
    const int cur = t & 1;
    if (t < 23) {
      const int kt = (t + 1) * 32;
      gl16(Ag + kt, &la[cur ^ 1][(wave * 16) * 32]);
      gl16(Ag + (size_t)64 * HIDV + kt, &la[cur ^ 1][(64 + wave * 16) * 32]);
      gl16(Bg + kt, &lb[cur ^ 1][(wave * 16) * 32]);
      gl16(Bg + (size_t)64 * HIDV + kt, &lb[cur ^ 1][(64 + wave * 16) * 32]);
    }
    bf16x8 af[4], bfr[4];
#pragma unroll
    for (int m = 0; m < 4; m++)
      af[m] = *reinterpret_cast<bf16x8*>(&la[cur][(wr + m * 16 + c) * 32 + g * 8]);
#pragma unroll
    for (int n = 0; n < 4; n++)
      bfr[n] = *reinterpret_cast<bf16x8*>(&lb[cur][(wc + n * 16 + c) * 32 + g * 8]);
#pragma unroll
    for (int m = 0; m < 4; m++)
#pragma unroll
      for (int n = 0; n < 4; n++)
        acc[m][n] = __builtin_amdgcn_mfma_f32_16x16x32_bf16(af[m], bfr[n], acc[m][n], 0, 0, 0);
    __syncthreads();
  }
  float bv4[4];
#pragma unroll
  for (int n = 0; n < 4; n++) bv4[n] = bias[n0 + wc + n * 16 + c];
  if (z < 2) {
    unsigned short* dst = (z == 0) ? Qh : Kh;
#pragma unroll
    for (int m = 0; m < 4; m++) {
      int rb_ = m0 + wr + m * 16 + g * 4;
#pragma unroll
      for (int n = 0; n < 4; n++) {
        int col = n0 + wc + n * 16 + c;
        int h = col >> 6, d = col & 63;
#pragma unroll
        for (int r = 0; r < 4; r++) {
          int row = rb_ + r;
          int b = row >> 10, s = row & 1023;
          dst[((size_t)(b * NH + h) * SEQ + s) * HD + d] = f2b(acc[m][n][r] + bv4[n]);
        }
      }
    }
  } else {
#pragma unroll
    for (int m = 0; m < 4; m++) {
      int rb_ = m0 + wr + m * 16 + g * 4;
      int b = rb_ >> 10, s = rb_ & 1023;
#pragma unroll
      for (int n = 0; n < 4; n++) {
        int col = n0 + wc + n * 16 + c;
        int h = col >> 6, d = col & 63;
        ushort4 o;
        o.x = f2b(acc[m][n][0] + bv4[n]);
        o.y = f2b(acc[m][n][1] + bv4[n]);
        o.z = f2b(acc[m][n][2] + bv4[n]);
        o.w = f2b(acc[m][n][3] + bv4[n]);
        *reinterpret_cast<ushort4*>(&VT[((size_t)(b * NH + h) * HD + d) * SEQ + s]) = o;
      }
    }
  }
}

// ---------- fused attention: SINGLE sweep, p~ kept in REGISTERS (pst[16][4]) ----------
// QK^T once; p~=exp2(s*c) packed bf16x2 into 128 VGPRs (static idx, full unroll);
// PV on unnormalized p~ via small per-wave lp bounce; probs written at end from
// regs * linv (posted store burst). LDS stays 45KB; VGPR ~230 -> ~2 blocks/CU.
#define EXPC 0.18033688f /* 0.125 * log2(e) */
__global__ __launch_bounds__(256) void attn_fused(
    const unsigned short* __restrict__ Qh, const unsigned short* __restrict__ Kh,
    const unsigned short* __restrict__ VT,
    float* __restrict__ probs, unsigned short* __restrict__ CTX) {
  __shared__ __align__(16) unsigned short ldsk[2][64 * 72];
  __shared__ __align__(16) unsigned short ldsv[2][64 * 72];
  __shared__ __align__(16) unsigned short lp[64 * 72];
  const int lin = blockIdx.x;
  const int swz = (lin & 7) * 96 + (lin >> 3);
  const int bh = swz >> 4, rb = (swz & 15) * QBLK;
  const int b = bh / NH, h = bh - b * NH;
  const unsigned short* Qp = Qh + (size_t)bh * SEQ * HD;
  const unsigned short* Kp = Kh + (size_t)bh * SEQ * HD;
  const unsigned short* Vp = VT + (size_t)bh * HD * SEQ;
  float* P = probs + (size_t)bh * SEQ * SEQ;
  const int tid = threadIdx.x, wave = tid >> 6, lane = tid & 63, g = lane >> 4, c = lane & 15;
  const int wrow = wave * 16;
  const int str = tid >> 3;
  const int stc = (tid & 7) * 8;

  bf16x8 aq[2];
#pragma unroll
  for (int ks = 0; ks < 2; ks++)
    aq[ks] = *reinterpret_cast<const bf16x8*>(&Qp[(size_t)(rb + wrow + c) * HD + ks * 32 + g * 8]);

  i32x4 kr0, kr1, vr0, vr1;
  // prologue: stage tile 0 K+V
  kr0 = *reinterpret_cast<const i32x4*>(&Kp[(size_t)str * HD + stc]);
  kr1 = *reinterpret_cast<const i32x4*>(&Kp[(size_t)(str + 32) * HD + stc]);
  vr0 = *reinterpret_cast<const i32x4*>(&Vp[(size_t)str * SEQ + stc]);
  vr1 = *reinterpret_cast<const i32x4*>(&Vp[(size_t)(str + 32) * SEQ + stc]);
  *reinterpret_cast<i32x4*>(&ldsk[0][str * 72 + stc]) = kr0;
  *reinterpret_cast<i32x4*>(&ldsk[0][(str + 32) * 72 + stc]) = kr1;
  *reinterpret_cast<i32x4*>(&ldsv[0][str * 72 + stc]) = vr0;
  *reinterpret_cast<i32x4*>(&ldsv[0][(str + 32) * 72 + stc]) = vr1;
  bar_lgkm();

  uint2 pst[16][4];  // packed bf16 p~ — MUST stay in regs (all indices static)
  float lsum = 0.f;
  f32x4 acc[4] = {};
#pragma unroll
  for (int ct = 0; ct < 16; ct++) {
    const int cur = ct & 1;
    if (ct < 15) {
      kr0 = *reinterpret_cast<const i32x4*>(&Kp[(size_t)((ct + 1) * 64 + str) * HD + stc]);
      kr1 = *reinterpret_cast<const i32x4*>(&Kp[(size_t)((ct + 1) * 64 + str + 32) * HD + stc]);
      vr0 = *reinterpret_cast<const i32x4*>(&Vp[(size_t)str * SEQ + (ct + 1) * 64 + stc]);
      vr1 = *reinterpret_cast<const i32x4*>(&Vp[(size_t)(str + 32) * SEQ + (ct + 1) * 64 + stc]);
    }
    f32x4 sreg[4] = {};
    __builtin_amdgcn_s_setprio(1);
#pragma unroll
    for (int ks = 0; ks < 2; ks++) {
      bf16x8 kf[4];
#pragma unroll
      for (int kb = 0; kb < 4; kb++)
        kf[kb] = *reinterpret_cast<bf16x8*>(&ldsk[cur][(kb * 16 + c) * 72 + ks * 32 + g * 8]);
#pragma unroll
      for (int kb = 0; kb < 4; kb++)
        sreg[kb] = __builtin_amdgcn_mfma_f32_16x16x32_bf16(kf[kb], aq[ks], sreg[kb], 0, 0, 0);
    }
    __builtin_amdgcn_s_setprio(0);
    // p~ = exp2(s*EXPC): keep packed in regs + lp bounce for PV A-operand
    {
#pragma unroll
      for (int kb = 0; kb < 4; kb++) {
        f32x4 p;
#pragma unroll
        for (int r = 0; r < 4; r++) {
          p[r] = __builtin_amdgcn_exp2f(sreg[kb][r] * EXPC);
          lsum += p[r];
        }
        uint2 pk;
        pk.x = (unsigned)f2b(p[0]) | ((unsigned)f2b(p[1]) << 16);
        pk.y = (unsigned)f2b(p[2]) | ((unsigned)f2b(p[3]) << 16);
        pst[ct][kb] = pk;
        *reinterpret_cast<uint2*>(&lp[(wrow + c) * 72 + kb * 16 + g * 4]) = pk;
      }
    }
    // PV with unnormalized p~
    __builtin_amdgcn_s_setprio(1);
#pragma unroll
    for (int ks = 0; ks < 2; ks++) {
      bf16x8 pa, vf[4];
      pa = *reinterpret_cast<bf16x8*>(&lp[(wrow + c) * 72 + ks * 32 + g * 8]);
#pragma unroll
      for (int db = 0; db < 4; db++)
        vf[db] = *reinterpret_cast<bf16x8*>(&ldsv[cur][(db * 16 + c) * 72 + ks * 32 + g * 8]);
#pragma unroll
      for (int db = 0; db < 4; db++)
        acc[db] = __builtin_amdgcn_mfma_f32_16x16x32_bf16(pa, vf[db], acc[db], 0, 0, 0);
    }
    __builtin_amdgcn_s_setprio(0);
    if (ct < 15) {
      *reinterpret_cast<i32x4*>(&ldsk[cur ^ 1][str * 72 + stc]) = kr0;
      *reinterpret_cast<i32x4*>(&ldsk[cur ^ 1][(str + 32) * 72 + stc]) = kr1;
      *reinterpret_cast<i32x4*>(&ldsv[cur ^ 1][str * 72 + stc]) = vr0;
      *reinterpret_cast<i32x4*>(&ldsv[cur ^ 1][(str + 32) * 72 + stc]) = vr1;
      bar_lgkm();  // single barrier per tile
    }
  }

  // ---- normalization: linv for own row (wrow+c) after cross-g reduce ----
  float s = lsum;
  s += __shfl_xor(s, 16);
  s += __shfl_xor(s, 32);
  const float linv = 1.f / s;

  // ---- probs burst: pst * linv -> f32 stores (posted; ride across barriers) ----
  {
    float* Prow = &P[(size_t)(rb + wrow + c) * SEQ];
#pragma unroll
    for (int ct = 0; ct < 16; ct++)
#pragma unroll
      for (int kb = 0; kb < 4; kb++) {
        uint2 pk = pst[ct][kb];
        float4 o;
        o.x = b2f((unsigned short)(pk.x & 0xffff)) * linv;
        o.y = b2f((unsigned short)(pk.x >> 16)) * linv;
        o.z = b2f((unsigned short)(pk.y & 0xffff)) * linv;
        o.w = b2f((unsigned short)(pk.y >> 16)) * linv;
        *reinterpret_cast<float4*>(&Prow[ct * 64 + kb * 16 + g * 4]) = o;
      }
  }

  // ---- CTX epilogue: scale acc by per-row linv (rows g*4+r via shfl) ----
  float lvr[4];
#pragma unroll
  for (int r = 0; r < 4; r++) lvr[r] = __shfl(linv, g * 4 + r);  // lane c'=g*4+r, g'=0
  bar_lgkm();  // all waves done with lp/ldsk/ldsv reads before repurpose
#pragma unroll
  for (int db = 0; db < 4; db++)
#pragma unroll
    for (int r = 0; r < 4; r++)
      lp[(wrow + g * 4 + r) * 72 + db * 16 + c] = f2b(acc[db][r] * lvr[r]);
  bar_lgkm();
  {
    const int q = tid >> 2, seg = (tid & 3) * 16;
    const unsigned short* src = &lp[q * 72 + seg];
    unsigned short* dst = &CTX[(size_t)(b * SEQ + rb + q) * HIDV + h * HD + seg];
    i32x4 t0 = *reinterpret_cast<const i32x4*>(&src[0]);
    i32x4 t1 = *reinterpret_cast<const i32x4*>(&src[8]);
    *reinterpret_cast<i32x4*>(&dst[0]) = t0;
    *reinterpret_cast<i32x4*>(&dst[8]) = t1;
  }
}

// ---------- output projection: 64x128 tile (384 blocks), T3-min pipeline ----------
__global__ __launch_bounds__(256) void proj_gemm(
    const unsigned short* __restrict__ Ab, const unsigned short* __restrict__ Wb,
    const float* __restrict__ bias, float* __restrict__ out) {
  __shared__ __align__(16) unsigned short la[2][64 * 32];
  __shared__ __align__(16) unsigned short lb[2][128 * 32];
  const int m0 = blockIdx.x * 64, n0 = blockIdx.y * 128;
  const int tid = threadIdx.x;
  const int wave = tid >> 6, lane = tid & 63, g = lane >> 4, c = lane & 15;
  const int wr = (wave >> 1) * 32, wc = (wave & 1) * 64;
  const int srb = wave * 16 + (lane >> 2);
  const int scol = (lane & 3) * 8;
  const unsigned short* Ag = &Ab[(size_t)(m0 + srb) * HIDV + scol];
  const unsigned short* Bg = &Wb[(size_t)(n0 + srb) * HIDV + scol];

#define PROJ_STAGE(buf, kt)                                               \
  do {                                                                    \
    gl16(Ag + (kt), &la[buf][(wave * 16) * 32]);                          \
    gl16(Bg + (kt), &lb[buf][(wave * 16) * 32]);                          \
    gl16(Bg + (size_t)64 * HIDV + (kt), &lb[buf][(64 + wave * 16) * 32]); \
  } while (0)

  PROJ_STAGE(0, 0);
  __syncthreads();

  f32x4 acc[2][4] = {};
  for (int t = 0; t < 24; t++) {
    const int cur = t & 1;
    if (t < 23) PROJ_STAGE(cur ^ 1, (t + 1) * 32);
    bf16x8 af[2], bfr[4];
#pragma unroll
    for (int m = 0; m < 2; m++)
      af[m] = *reinterpret_cast<bf16x8*>(&la[cur][(wr + m * 16 + c) * 32 + g * 8]);
#pragma unroll
    for (int n = 0; n < 4; n++)
      bfr[n] = *reinterpret_cast<bf16x8*>(&lb[cur][(wc + n * 16 + c) * 32 + g * 8]);
#pragma unroll
    for (int m = 0; m < 2; m++)
#pragma unroll
      for (int n = 0; n < 4; n++)
        acc[m][n] = __builtin_amdgcn_mfma_f32_16x16x32_bf16(af[m], bfr[n], acc[m][n], 0, 0, 0);
    __syncthreads();
  }
#undef PROJ_STAGE
  float bv4[4];
#pragma unroll
  for (int n = 0; n < 4; n++) bv4[n] = bias[n0 + wc + n * 16 + c];
#pragma unroll
  for (int m = 0; m < 2; m++) {
    int rb_ = m0 + wr + m * 16 + g * 4;
#pragma unroll
    for (int n = 0; n < 4; n++) {
      int col = n0 + wc + n * 16 + c;
#pragma unroll
      for (int r = 0; r < 4; r++)
        out[(size_t)(rb_ + r) * HIDV + col] = acc[m][n][r] + bv4[n];
    }
  }
}

extern "C" void kernel_launch(void* const* d_in, const int* in_sizes, int n_in,
                              void* d_out, int out_size, void* d_ws, size_t ws_size,
                              hipStream_t stream) {
  const float* X  = (const float*)d_in[0];
  const float* Wq = (const float*)d_in[1];
  const float* bq = (const float*)d_in[2];
  const float* Wk = (const float*)d_in[3];
  const float* bk = (const float*)d_in[4];
  const float* Wv = (const float*)d_in[5];
  const float* bv = (const float*)d_in[6];
  const float* Wo = (const float*)d_in[7];
  const float* bo = (const float*)d_in[8];
  float* out = (float*)d_out;
  float* probs = out + 3145728;  // output 1 region

  unsigned short* Xb  = (unsigned short*)d_ws;        // [4096,768]
  unsigned short* Wqb = Xb + 3145728;                 // [768,768]
  unsigned short* Wkb = Wqb + 589824;
  unsigned short* Wvb = Wkb + 589824;
  unsigned short* Wob = Wvb + 589824;
  unsigned short* Qh  = Wob + 589824;                 // [4,12,1024,64]
  unsigned short* Kh  = Qh + 3145728;
  unsigned short* VT  = Kh + 3145728;                 // [4,12,64,1024]
  unsigned short* CTX = VT + 3145728;                 // [4096,768]

  convert_all<<<5376, 256, 0, stream>>>(X, Wq, Wk, Wv, Wo, Xb);
  qkv_gemm<<<dim3(32, 6, 3), 256, 0, stream>>>(Xb, Wqb, Wkb, Wvb, bq, bk, bv, Qh, Kh, VT);
  attn_fused<<<dim3(768), 256, 0, stream>>>(Qh, Kh, VT, probs, CTX);
  proj_gemm<<<dim3(64, 6), 256, 0, stream>>>(CTX, Wob, bo, out);
}

// Round 13
// 131.871 us; speedup vs baseline: 1.2547x; 1.1239x over previous
//
#include <hip/hip_runtime.h>
#include <hip/hip_bf16.h>

typedef __attribute__((ext_vector_type(4))) float f32x4;
typedef __attribute__((ext_vector_type(8))) short bf16x8;
typedef __attribute__((ext_vector_type(4))) int i32x4;

#define SEQ 1024
#define HIDV 768
#define NH 12
#define HD 64
#define QBLK 64

static __device__ __forceinline__ unsigned short f2b(float f) {
  unsigned u = __builtin_bit_cast(unsigned, f);
  u = (u + 0x7fffu + ((u >> 16) & 1u)) >> 16;
  return (unsigned short)u;
}

static __device__ __forceinline__ void gl16(const unsigned short* g, unsigned short* l) {
  __builtin_amdgcn_global_load_lds(
      (const __attribute__((address_space(1))) unsigned int*)g,
      (__attribute__((address_space(3))) unsigned int*)l, 16, 0, 0);
}

// barrier that waits ONLY on LDS ops (keeps global stores/loads in flight)
static __device__ __forceinline__ void bar_lgkm() {
  asm volatile("s_waitcnt lgkmcnt(0)" ::: "memory");
  __builtin_amdgcn_sched_barrier(0);
  __builtin_amdgcn_s_barrier();
  __builtin_amdgcn_sched_barrier(0);
}

// ---------- convert f32 inputs -> bf16 (X, Wq, Wk, Wv, Wo contiguous in ws) ----------
__global__ __launch_bounds__(256) void convert_all(
    const float* __restrict__ X, const float* __restrict__ Wq,
    const float* __restrict__ Wk, const float* __restrict__ Wv,
    const float* __restrict__ Wo, unsigned short* __restrict__ dst) {
  long i = (long)blockIdx.x * 256 + threadIdx.x;
  const long N4 = (3145728L + 4 * 589824L) / 4;
  if (i >= N4) return;
  long e = i * 4;
  const float* src; long off;
  if (e < 3145728L)      { src = X;  off = e; }
  else if (e < 3735552L) { src = Wq; off = e - 3145728L; }
  else if (e < 4325376L) { src = Wk; off = e - 3735552L; }
  else if (e < 4915200L) { src = Wv; off = e - 4325376L; }
  else                   { src = Wo; off = e - 4915200L; }
  const float4 v = *reinterpret_cast<const float4*>(src + off);
  ushort4 o;
  o.x = f2b(v.x); o.y = f2b(v.y); o.z = f2b(v.z); o.w = f2b(v.w);
  *reinterpret_cast<ushort4*>(dst + e) = o;
}

// ---------- fused QKV GEMM: T3-min pipeline (r6/r10 version, best measured) ----------
__global__ __launch_bounds__(256) void qkv_gemm(
    const unsigned short* __restrict__ Xb,
    const unsigned short* __restrict__ Wqb, const unsigned short* __restrict__ Wkb,
    const unsigned short* __restrict__ Wvb,
    const float* __restrict__ bq, const float* __restrict__ bk, const float* __restrict__ bv,
    unsigned short* __restrict__ Qh, unsigned short* __restrict__ Kh,
    unsigned short* __restrict__ VT) {
  __shared__ __align__(16) unsigned short la[2][128 * 32];
  __shared__ __align__(16) unsigned short lb[2][128 * 32];
  const int z = blockIdx.z;
  const unsigned short* Wb = (z == 0) ? Wqb : (z == 1) ? Wkb : Wvb;
  const float* bias = (z == 0) ? bq : (z == 1) ? bk : bv;
  const int m0 = blockIdx.x * 128, n0 = blockIdx.y * 128;
  const int tid = threadIdx.x;
  const int wave = tid >> 6, lane = tid & 63, g = lane >> 4, c = lane & 15;
  const int wr = (wave >> 1) * 64, wc = (wave & 1) * 64;

  const int sr = wave * 16 + (lane >> 2);
  const int scol = (lane & 3) * 8;
  const unsigned short* Ag = &Xb[(size_t)(m0 + sr) * HIDV + scol];
  const unsigned short* Bg = &Wb[(size_t)(n0 + sr) * HIDV + scol];

  gl16(Ag, &la[0][(wave * 16) * 32]);
  gl16(Ag + (size_t)64 * HIDV, &la[0][(64 + wave * 16) * 32]);
  gl16(Bg, &lb[0][(wave * 16) * 32]);
  gl16(Bg + (size_t)64 * HIDV, &lb[0][(64 + wave * 16) * 32]);
  __syncthreads();

  f32x4 acc[4][4] = {};
  for (int t = 0; t < 24; t++) {
    const int cur = t & 1;
    if (t < 23) {
      const int kt = (t + 1) * 32;
      gl16(Ag + kt, &la[cur ^ 1][(wave * 16) * 32]);
      gl16(Ag + (size_t)64 * HIDV + kt, &la[cur ^ 1][(64 + wave * 16) * 32]);
      gl16(Bg + kt, &lb[cur ^ 1][(wave * 16) * 32]);
      gl16(Bg + (size_t)64 * HIDV + kt, &lb[cur ^ 1][(64 + wave * 16) * 32]);
    }
    bf16x8 af[4], bfr[4];
#pragma unroll
    for (int m = 0; m < 4; m++)
      af[m] = *reinterpret_cast<bf16x8*>(&la[cur][(wr + m * 16 + c) * 32 + g * 8]);
#pragma unroll
    for (int n = 0; n < 4; n++)
      bfr[n] = *reinterpret_cast<bf16x8*>(&lb[cur][(wc + n * 16 + c) * 32 + g * 8]);
#pragma unroll
    for (int m = 0; m < 4; m++)
#pragma unroll
      for (int n = 0; n < 4; n++)
        acc[m][n] = __builtin_amdgcn_mfma_f32_16x16x32_bf16(af[m], bfr[n], acc[m][n], 0, 0, 0);
    __syncthreads();
  }
  float bv4[4];
#pragma unroll
  for (int n = 0; n < 4; n++) bv4[n] = bias[n0 + wc + n * 16 + c];
  if (z < 2) {
    unsigned short* dst = (z == 0) ? Qh : Kh;
#pragma unroll
    for (int m = 0; m < 4; m++) {
      int rb_ = m0 + wr + m * 16 + g * 4;
#pragma unroll
      for (int n = 0; n < 4; n++) {
        int col = n0 + wc + n * 16 + c;
        int h = col >> 6, d = col & 63;
#pragma unroll
        for (int r = 0; r < 4; r++) {
          int row = rb_ + r;
          int b = row >> 10, s = row & 1023;
          dst[((size_t)(b * NH + h) * SEQ + s) * HD + d] = f2b(acc[m][n][r] + bv4[n]);
        }
      }
    }
  } else {
#pragma unroll
    for (int m = 0; m < 4; m++) {
      int rb_ = m0 + wr + m * 16 + g * 4;
      int b = rb_ >> 10, s = rb_ & 1023;
#pragma unroll
      for (int n = 0; n < 4; n++) {
        int col = n0 + wc + n * 16 + c;
        int h = col >> 6, d = col & 63;
        ushort4 o;
        o.x = f2b(acc[m][n][0] + bv4[n]);
        o.y = f2b(acc[m][n][1] + bv4[n]);
        o.z = f2b(acc[m][n][2] + bv4[n]);
        o.w = f2b(acc[m][n][3] + bv4[n]);
        *reinterpret_cast<ushort4*>(&VT[((size_t)(b * NH + h) * HD + d) * SEQ + s]) = o;
      }
    }
  }
}

// ---------- fused attention: r9/r10 structure + NON-TEMPORAL probs stores ----------
#define EXPC 0.18033688f /* 0.125 * log2(e) */
__global__ __launch_bounds__(256) void attn_fused(
    const unsigned short* __restrict__ Qh, const unsigned short* __restrict__ Kh,
    const unsigned short* __restrict__ VT,
    float* __restrict__ probs, unsigned short* __restrict__ CTX) {
  __shared__ __align__(16) unsigned short ldsk[2][64 * 72];
  __shared__ __align__(16) unsigned short ldsv[2][64 * 72];
  __shared__ __align__(16) unsigned short lp[64 * 72];
  const int lin = blockIdx.x;
  const int swz = (lin & 7) * 96 + (lin >> 3);
  const int bh = swz >> 4, rb = (swz & 15) * QBLK;
  const int b = bh / NH, h = bh - b * NH;
  const unsigned short* Qp = Qh + (size_t)bh * SEQ * HD;
  const unsigned short* Kp = Kh + (size_t)bh * SEQ * HD;
  const unsigned short* Vp = VT + (size_t)bh * HD * SEQ;
  float* P = probs + (size_t)bh * SEQ * SEQ;
  const int tid = threadIdx.x, wave = tid >> 6, lane = tid & 63, g = lane >> 4, c = lane & 15;
  const int wrow = wave * 16;
  const int str = tid >> 3;
  const int stc = (tid & 7) * 8;

  bf16x8 aq[2];
#pragma unroll
  for (int ks = 0; ks < 2; ks++)
    aq[ks] = *reinterpret_cast<const bf16x8*>(&Qp[(size_t)(rb + wrow + c) * HD + ks * 32 + g * 8]);

  i32x4 kr0, kr1, vr0, vr1;
  kr0 = *reinterpret_cast<const i32x4*>(&Kp[(size_t)str * HD + stc]);
  kr1 = *reinterpret_cast<const i32x4*>(&Kp[(size_t)(str + 32) * HD + stc]);
  *reinterpret_cast<i32x4*>(&ldsk[0][str * 72 + stc]) = kr0;
  *reinterpret_cast<i32x4*>(&ldsk[0][(str + 32) * 72 + stc]) = kr1;
  bar_lgkm();

  // ---- sweep 1: row sums (1 barrier/tile) ----
  float lsum = 0.f;
  for (int ct = 0; ct < 16; ct++) {
    const int cur = ct & 1;
    if (ct < 15) {
      kr0 = *reinterpret_cast<const i32x4*>(&Kp[(size_t)((ct + 1) * 64 + str) * HD + stc]);
      kr1 = *reinterpret_cast<const i32x4*>(&Kp[(size_t)((ct + 1) * 64 + str + 32) * HD + stc]);
    }
    f32x4 sreg[4] = {};
    __builtin_amdgcn_s_setprio(1);
#pragma unroll
    for (int ks = 0; ks < 2; ks++) {
      bf16x8 kf[4];
#pragma unroll
      for (int kb = 0; kb < 4; kb++)
        kf[kb] = *reinterpret_cast<bf16x8*>(&ldsk[cur][(kb * 16 + c) * 72 + ks * 32 + g * 8]);
#pragma unroll
      for (int kb = 0; kb < 4; kb++)
        sreg[kb] = __builtin_amdgcn_mfma_f32_16x16x32_bf16(kf[kb], aq[ks], sreg[kb], 0, 0, 0);
    }
    __builtin_amdgcn_s_setprio(0);
#pragma unroll
    for (int kb = 0; kb < 4; kb++)
#pragma unroll
      for (int r = 0; r < 4; r++)
        lsum += __builtin_amdgcn_exp2f(sreg[kb][r] * EXPC);
    if (ct < 15) {
      *reinterpret_cast<i32x4*>(&ldsk[cur ^ 1][str * 72 + stc]) = kr0;
      *reinterpret_cast<i32x4*>(&ldsk[cur ^ 1][(str + 32) * 72 + stc]) = kr1;
      bar_lgkm();
    }
  }
  float s = lsum;
  s += __shfl_xor(s, 16);
  s += __shfl_xor(s, 32);
  const float linv = 1.f / s;

  // ---- sweep 2 prologue: stage K0 + V0 ----
  kr0 = *reinterpret_cast<const i32x4*>(&Kp[(size_t)str * HD + stc]);
  kr1 = *reinterpret_cast<const i32x4*>(&Kp[(size_t)(str + 32) * HD + stc]);
  vr0 = *reinterpret_cast<const i32x4*>(&Vp[(size_t)str * SEQ + stc]);
  vr1 = *reinterpret_cast<const i32x4*>(&Vp[(size_t)(str + 32) * SEQ + stc]);
  *reinterpret_cast<i32x4*>(&ldsk[0][str * 72 + stc]) = kr0;
  *reinterpret_cast<i32x4*>(&ldsk[0][(str + 32) * 72 + stc]) = kr1;
  *reinterpret_cast<i32x4*>(&ldsv[0][str * 72 + stc]) = vr0;
  *reinterpret_cast<i32x4*>(&ldsv[0][(str + 32) * 72 + stc]) = vr1;
  bar_lgkm();

  // ---- sweep 2: QKT -> probs(nt) -> PV -> stage-next -> ONE barrier ----
  f32x4 acc[4] = {};
  for (int ct = 0; ct < 16; ct++) {
    const int cur = ct & 1;
    if (ct < 15) {
      kr0 = *reinterpret_cast<const i32x4*>(&Kp[(size_t)((ct + 1) * 64 + str) * HD + stc]);
      kr1 = *reinterpret_cast<const i32x4*>(&Kp[(size_t)((ct + 1) * 64 + str + 32) * HD + stc]);
      vr0 = *reinterpret_cast<const i32x4*>(&Vp[(size_t)str * SEQ + (ct + 1) * 64 + stc]);
      vr1 = *reinterpret_cast<const i32x4*>(&Vp[(size_t)(str + 32) * SEQ + (ct + 1) * 64 + stc]);
    }
    f32x4 sreg[4] = {};
    __builtin_amdgcn_s_setprio(1);
#pragma unroll
    for (int ks = 0; ks < 2; ks++) {
      bf16x8 kf[4];
#pragma unroll
      for (int kb = 0; kb < 4; kb++)
        kf[kb] = *reinterpret_cast<bf16x8*>(&ldsk[cur][(kb * 16 + c) * 72 + ks * 32 + g * 8]);
#pragma unroll
      for (int kb = 0; kb < 4; kb++)
        sreg[kb] = __builtin_amdgcn_mfma_f32_16x16x32_bf16(kf[kb], aq[ks], sreg[kb], 0, 0, 0);
    }
    __builtin_amdgcn_s_setprio(0);
    {
      float* Prow = &P[(size_t)(rb + wrow + c) * SEQ + ct * 64];
#pragma unroll
      for (int kb = 0; kb < 4; kb++) {
        f32x4 p;
#pragma unroll
        for (int r = 0; r < 4; r++)
          p[r] = __builtin_amdgcn_exp2f(sreg[kb][r] * EXPC) * linv;
        // NT store: probs is write-once/never-read -> keep it out of L2 so K/V stay hot
        __builtin_nontemporal_store(p, reinterpret_cast<f32x4*>(&Prow[kb * 16 + g * 4]));
        uint2 pk;
        pk.x = (unsigned)f2b(p[0]) | ((unsigned)f2b(p[1]) << 16);
        pk.y = (unsigned)f2b(p[2]) | ((unsigned)f2b(p[3]) << 16);
        *reinterpret_cast<uint2*>(&lp[(wrow + c) * 72 + kb * 16 + g * 4]) = pk;
      }
    }
    __builtin_amdgcn_s_setprio(1);
#pragma unroll
    for (int ks = 0; ks < 2; ks++) {
      bf16x8 pa, vf[4];
      pa = *reinterpret_cast<bf16x8*>(&lp[(wrow + c) * 72 + ks * 32 + g * 8]);
#pragma unroll
      for (int db = 0; db < 4; db++)
        vf[db] = *reinterpret_cast<bf16x8*>(&ldsv[cur][(db * 16 + c) * 72 + ks * 32 + g * 8]);
#pragma unroll
      for (int db = 0; db < 4; db++)
        acc[db] = __builtin_amdgcn_mfma_f32_16x16x32_bf16(pa, vf[db], acc[db], 0, 0, 0);
    }
    __builtin_amdgcn_s_setprio(0);
    if (ct < 15) {
      *reinterpret_cast<i32x4*>(&ldsk[cur ^ 1][str * 72 + stc]) = kr0;
      *reinterpret_cast<i32x4*>(&ldsk[cur ^ 1][(str + 32) * 72 + stc]) = kr1;
      *reinterpret_cast<i32x4*>(&ldsv[cur ^ 1][str * 72 + stc]) = vr0;
      *reinterpret_cast<i32x4*>(&ldsv[cur ^ 1][(str + 32) * 72 + stc]) = vr1;
      bar_lgkm();
    }
  }

  // ---- CTX epilogue ----
  bar_lgkm();
#pragma unroll
  for (int db = 0; db < 4; db++)
#pragma unroll
    for (int r = 0; r < 4; r++)
      lp[(wrow + g * 4 + r) * 72 + db * 16 + c] = f2b(acc[db][r]);
  bar_lgkm();
  {
    const int q = tid >> 2, seg = (tid & 3) * 16;
    const unsigned short* src = &lp[q * 72 + seg];
    unsigned short* dst = &CTX[(size_t)(b * SEQ + rb + q) * HIDV + h * HD + seg];
    i32x4 t0 = *reinterpret_cast<const i32x4*>(&src[0]);
    i32x4 t1 = *reinterpret_cast<const i32x4*>(&src[8]);
    *reinterpret_cast<i32x4*>(&dst[0]) = t0;
    *reinterpret_cast<i32x4*>(&dst[8]) = t1;
  }
}

// ---------- output projection: 64x128 tile (384 blocks), T3-min pipeline ----------
__global__ __launch_bounds__(256) void proj_gemm(
    const unsigned short* __restrict__ Ab, const unsigned short* __restrict__ Wb,
    const float* __restrict__ bias, float* __restrict__ out) {
  __shared__ __align__(16) unsigned short la[2][64 * 32];
  __shared__ __align__(16) unsigned short lb[2][128 * 32];
  const int m0 = blockIdx.x * 64, n0 = blockIdx.y * 128;
  const int tid = threadIdx.x;
  const int wave = tid >> 6, lane = tid & 63, g = lane >> 4, c = lane & 15;
  const int wr = (wave >> 1) * 32, wc = (wave & 1) * 64;
  const int srb = wave * 16 + (lane >> 2);
  const int scol = (lane & 3) * 8;
  const unsigned short* Ag = &Ab[(size_t)(m0 + srb) * HIDV + scol];
  const unsigned short* Bg = &Wb[(size_t)(n0 + srb) * HIDV + scol];

#define PROJ_STAGE(buf, kt)                                               \
  do {                                                                    \
    gl16(Ag + (kt), &la[buf][(wave * 16) * 32]);                          \
    gl16(Bg + (kt), &lb[buf][(wave * 16) * 32]);                          \
    gl16(Bg + (size_t)64 * HIDV + (kt), &lb[buf][(64 + wave * 16) * 32]); \
  } while (0)

  PROJ_STAGE(0, 0);
  __syncthreads();

  f32x4 acc[2][4] = {};
  for (int t = 0; t < 24; t++) {
    const int cur = t & 1;
    if (t < 23) PROJ_STAGE(cur ^ 1, (t + 1) * 32);
    bf16x8 af[2], bfr[4];
#pragma unroll
    for (int m = 0; m < 2; m++)
      af[m] = *reinterpret_cast<bf16x8*>(&la[cur][(wr + m * 16 + c) * 32 + g * 8]);
#pragma unroll
    for (int n = 0; n < 4; n++)
      bfr[n] = *reinterpret_cast<bf16x8*>(&lb[cur][(wc + n * 16 + c) * 32 + g * 8]);
#pragma unroll
    for (int m = 0; m < 2; m++)
#pragma unroll
      for (int n = 0; n < 4; n++)
        acc[m][n] = __builtin_amdgcn_mfma_f32_16x16x32_bf16(af[m], bfr[n], acc[m][n], 0, 0, 0);
    __syncthreads();
  }
#undef PROJ_STAGE
  float bv4[4];
#pragma unroll
  for (int n = 0; n < 4; n++) bv4[n] = bias[n0 + wc + n * 16 + c];
#pragma unroll
  for (int m = 0; m < 2; m++) {
    int rb_ = m0 + wr + m * 16 + g * 4;
#pragma unroll
    for (int n = 0; n < 4; n++) {
      int col = n0 + wc + n * 16 + c;
#pragma unroll
      for (int r = 0; r < 4; r++)
        out[(size_t)(rb_ + r) * HIDV + col] = acc[m][n][r] + bv4[n];
    }
  }
}

extern "C" void kernel_launch(void* const* d_in, const int* in_sizes, int n_in,
                              void* d_out, int out_size, void* d_ws, size_t ws_size,
                              hipStream_t stream) {
  const float* X  = (const float*)d_in[0];
  const float* Wq = (const float*)d_in[1];
  const float* bq = (const float*)d_in[2];
  const float* Wk = (const float*)d_in[3];
  const float* bk = (const float*)d_in[4];
  const float* Wv = (const float*)d_in[5];
  const float* bv = (const float*)d_in[6];
  const float* Wo = (const float*)d_in[7];
  const float* bo = (const float*)d_in[8];
  float* out = (float*)d_out;
  float* probs = out + 3145728;  // output 1 region

  unsigned short* Xb  = (unsigned short*)d_ws;        // [4096,768]
  unsigned short* Wqb = Xb + 3145728;                 // [768,768]
  unsigned short* Wkb = Wqb + 589824;
  unsigned short* Wvb = Wkb + 589824;
  unsigned short* Wob = Wvb + 589824;
  unsigned short* Qh  = Wob + 589824;                 // [4,12,1024,64]
  unsigned short* Kh  = Qh + 3145728;
  unsigned short* VT  = Kh + 3145728;                 // [4,12,64,1024]
  unsigned short* CTX = VT + 3145728;                 // [4096,768]

  convert_all<<<5376, 256, 0, stream>>>(X, Wq, Wk, Wv, Wo, Xb);
  qkv_gemm<<<dim3(32, 6, 3), 256, 0, stream>>>(Xb, Wqb, Wkb, Wvb, bq, bk, bv, Qh, Kh, VT);
  attn_fused<<<dim3(768), 256, 0, stream>>>(Qh, Kh, VT, probs, CTX);
  proj_gemm<<<dim3(64, 6), 256, 0, stream>>>(CTX, Wob, bo, out);
}

// Round 14
// 105.480 us; speedup vs baseline: 1.5686x; 1.2502x over previous
//
#include <hip/hip_runtime.h>
#include <hip/hip_bf16.h>

typedef __attribute__((ext_vector_type(4))) float f32x4;
typedef __attribute__((ext_vector_type(8))) short bf16x8;
typedef __attribute__((ext_vector_type(4))) int i32x4;

#define SEQ 1024
#define HIDV 768
#define NH 12
#define HD 64
#define QBLK 64

static __device__ __forceinline__ unsigned short f2b(float f) {
  unsigned u = __builtin_bit_cast(unsigned, f);
  u = (u + 0x7fffu + ((u >> 16) & 1u)) >> 16;
  return (unsigned short)u;
}

static __device__ __forceinline__ void gl16(const unsigned short* g, unsigned short* l) {
  __builtin_amdgcn_global_load_lds(
      (const __attribute__((address_space(1))) unsigned int*)g,
      (__attribute__((address_space(3))) unsigned int*)l, 16, 0, 0);
}

// barrier that waits ONLY on LDS ops (keeps global stores/loads in flight)
static __device__ __forceinline__ void bar_lgkm() {
  asm volatile("s_waitcnt lgkmcnt(0)" ::: "memory");
  __builtin_amdgcn_sched_barrier(0);
  __builtin_amdgcn_s_barrier();
  __builtin_amdgcn_sched_barrier(0);
}

// ---------- convert f32 inputs -> bf16 (X, Wq, Wk, Wv, Wo contiguous in ws) ----------
__global__ __launch_bounds__(256) void convert_all(
    const float* __restrict__ X, const float* __restrict__ Wq,
    const float* __restrict__ Wk, const float* __restrict__ Wv,
    const float* __restrict__ Wo, unsigned short* __restrict__ dst) {
  long i = (long)blockIdx.x * 256 + threadIdx.x;
  const long N4 = (3145728L + 4 * 589824L) / 4;
  if (i >= N4) return;
  long e = i * 4;
  const float* src; long off;
  if (e < 3145728L)      { src = X;  off = e; }
  else if (e < 3735552L) { src = Wq; off = e - 3145728L; }
  else if (e < 4325376L) { src = Wk; off = e - 3735552L; }
  else if (e < 4915200L) { src = Wv; off = e - 4325376L; }
  else                   { src = Wo; off = e - 4915200L; }
  const float4 v = *reinterpret_cast<const float4*>(src + off);
  ushort4 o;
  o.x = f2b(v.x); o.y = f2b(v.y); o.z = f2b(v.z); o.w = f2b(v.w);
  *reinterpret_cast<ushort4*>(dst + e) = o;
}

// ---------- fused QKV GEMM: T3-min pipeline + vectorized Q/K epilogue ----------
__global__ __launch_bounds__(256) void qkv_gemm(
    const unsigned short* __restrict__ Xb,
    const unsigned short* __restrict__ Wqb, const unsigned short* __restrict__ Wkb,
    const unsigned short* __restrict__ Wvb,
    const float* __restrict__ bq, const float* __restrict__ bk, const float* __restrict__ bv,
    unsigned short* __restrict__ Qh, unsigned short* __restrict__ Kh,
    unsigned short* __restrict__ VT) {
  // 34816 B: staging la=[0,8192) lb=[8192,16384) ushorts; epilogue reuses all as [128][136]
  __shared__ __align__(16) unsigned short smem[17408];
#define LA(buf) (smem + (buf) * 4096)
#define LB(buf) (smem + 8192 + (buf) * 4096)
  const int z = blockIdx.z;
  const unsigned short* Wb = (z == 0) ? Wqb : (z == 1) ? Wkb : Wvb;
  const float* bias = (z == 0) ? bq : (z == 1) ? bk : bv;
  const int m0 = blockIdx.x * 128, n0 = blockIdx.y * 128;
  const int tid = threadIdx.x;
  const int wave = tid >> 6, lane = tid & 63, g = lane >> 4, c = lane & 15;
  const int wr = (wave >> 1) * 64, wc = (wave & 1) * 64;

  const int sr = wave * 16 + (lane >> 2);
  const int scol = (lane & 3) * 8;
  const unsigned short* Ag = &Xb[(size_t)(m0 + sr) * HIDV + scol];
  const unsigned short* Bg = &Wb[(size_t)(n0 + sr) * HIDV + scol];

  gl16(Ag, LA(0) + (wave * 16) * 32);
  gl16(Ag + (size_t)64 * HIDV, LA(0) + (64 + wave * 16) * 32);
  gl16(Bg, LB(0) + (wave * 16) * 32);
  gl16(Bg + (size_t)64 * HIDV, LB(0) + (64 + wave * 16) * 32);
  __syncthreads();

  f32x4 acc[4][4] = {};
  for (int t = 0; t < 24; t++) {
    const int cur = t & 1;
    if (t < 23) {
      const int kt = (t + 1) * 32;
      gl16(Ag + kt, LA(cur ^ 1) + (wave * 16) * 32);
      gl16(Ag + (size_t)64 * HIDV + kt, LA(cur ^ 1) + (64 + wave * 16) * 32);
      gl16(Bg + kt, LB(cur ^ 1) + (wave * 16) * 32);
      gl16(Bg + (size_t)64 * HIDV + kt, LB(cur ^ 1) + (64 + wave * 16) * 32);
    }
    bf16x8 af[4], bfr[4];
#pragma unroll
    for (int m = 0; m < 4; m++)
      af[m] = *reinterpret_cast<bf16x8*>(LA(cur) + (wr + m * 16 + c) * 32 + g * 8);
#pragma unroll
    for (int n = 0; n < 4; n++)
      bfr[n] = *reinterpret_cast<bf16x8*>(LB(cur) + (wc + n * 16 + c) * 32 + g * 8);
#pragma unroll
    for (int m = 0; m < 4; m++)
#pragma unroll
      for (int n = 0; n < 4; n++)
        acc[m][n] = __builtin_amdgcn_mfma_f32_16x16x32_bf16(af[m], bfr[n], acc[m][n], 0, 0, 0);
    __syncthreads();
  }
  float bv4[4];
#pragma unroll
  for (int n = 0; n < 4; n++) bv4[n] = bias[n0 + wc + n * 16 + c];
  if (z < 2) {
    // bounce acc through LDS [128][136] -> 16B coalesced head-split stores
#pragma unroll
    for (int m = 0; m < 4; m++)
#pragma unroll
      for (int n = 0; n < 4; n++)
#pragma unroll
        for (int r = 0; r < 4; r++)
          smem[(wr + m * 16 + g * 4 + r) * 136 + wc + n * 16 + c] =
              f2b(acc[m][n][r] + bv4[n]);
    __syncthreads();
    {
      const int hh = tid >> 7, row = tid & 127;
      const int grow = m0 + row;
      const int b_ = grow >> 10, s_ = grow & 1023;
      const int hgl = (n0 >> 6) + hh;
      unsigned short* dst =
          ((z == 0) ? Qh : Kh) + ((size_t)(b_ * NH + hgl) * SEQ + s_) * HD;
      const unsigned short* src = &smem[row * 136 + hh * 64];
#pragma unroll
      for (int j = 0; j < 8; j++)
        *reinterpret_cast<i32x4*>(&dst[j * 8]) =
            *reinterpret_cast<const i32x4*>(&src[j * 8]);
    }
  } else {
#pragma unroll
    for (int m = 0; m < 4; m++) {
      int rb_ = m0 + wr + m * 16 + g * 4;
      int b = rb_ >> 10, s = rb_ & 1023;
#pragma unroll
      for (int n = 0; n < 4; n++) {
        int col = n0 + wc + n * 16 + c;
        int h = col >> 6, d = col & 63;
        ushort4 o;
        o.x = f2b(acc[m][n][0] + bv4[n]);
        o.y = f2b(acc[m][n][1] + bv4[n]);
        o.z = f2b(acc[m][n][2] + bv4[n]);
        o.w = f2b(acc[m][n][3] + bv4[n]);
        *reinterpret_cast<ushort4*>(&VT[((size_t)(b * NH + h) * HD + d) * SEQ + s]) = o;
      }
    }
  }
#undef LA
#undef LB
}

// ---------- fused attention: r9/r10 version (best measured) ----------
#define EXPC 0.18033688f /* 0.125 * log2(e) */
__global__ __launch_bounds__(256) void attn_fused(
    const unsigned short* __restrict__ Qh, const unsigned short* __restrict__ Kh,
    const unsigned short* __restrict__ VT,
    float* __restrict__ probs, unsigned short* __restrict__ CTX) {
  __shared__ __align__(16) unsigned short ldsk[2][64 * 72];
  __shared__ __align__(16) unsigned short ldsv[2][64 * 72];
  __shared__ __align__(16) unsigned short lp[64 * 72];
  const int lin = blockIdx.x;
  const int swz = (lin & 7) * 96 + (lin >> 3);
  const int bh = swz >> 4, rb = (swz & 15) * QBLK;
  const int b = bh / NH, h = bh - b * NH;
  const unsigned short* Qp = Qh + (size_t)bh * SEQ * HD;
  const unsigned short* Kp = Kh + (size_t)bh * SEQ * HD;
  const unsigned short* Vp = VT + (size_t)bh * HD * SEQ;
  float* P = probs + (size_t)bh * SEQ * SEQ;
  const int tid = threadIdx.x, wave = tid >> 6, lane = tid & 63, g = lane >> 4, c = lane & 15;
  const int wrow = wave * 16;
  const int str = tid >> 3;
  const int stc = (tid & 7) * 8;

  bf16x8 aq[2];
#pragma unroll
  for (int ks = 0; ks < 2; ks++)
    aq[ks] = *reinterpret_cast<const bf16x8*>(&Qp[(size_t)(rb + wrow + c) * HD + ks * 32 + g * 8]);

  i32x4 kr0, kr1, vr0, vr1;
  kr0 = *reinterpret_cast<const i32x4*>(&Kp[(size_t)str * HD + stc]);
  kr1 = *reinterpret_cast<const i32x4*>(&Kp[(size_t)(str + 32) * HD + stc]);
  *reinterpret_cast<i32x4*>(&ldsk[0][str * 72 + stc]) = kr0;
  *reinterpret_cast<i32x4*>(&ldsk[0][(str + 32) * 72 + stc]) = kr1;
  bar_lgkm();

  // ---- sweep 1: row sums (1 barrier/tile) ----
  float lsum = 0.f;
  for (int ct = 0; ct < 16; ct++) {
    const int cur = ct & 1;
    if (ct < 15) {
      kr0 = *reinterpret_cast<const i32x4*>(&Kp[(size_t)((ct + 1) * 64 + str) * HD + stc]);
      kr1 = *reinterpret_cast<const i32x4*>(&Kp[(size_t)((ct + 1) * 64 + str + 32) * HD + stc]);
    }
    f32x4 sreg[4] = {};
    __builtin_amdgcn_s_setprio(1);
#pragma unroll
    for (int ks = 0; ks < 2; ks++) {
      bf16x8 kf[4];
#pragma unroll
      for (int kb = 0; kb < 4; kb++)
        kf[kb] = *reinterpret_cast<bf16x8*>(&ldsk[cur][(kb * 16 + c) * 72 + ks * 32 + g * 8]);
#pragma unroll
      for (int kb = 0; kb < 4; kb++)
        sreg[kb] = __builtin_amdgcn_mfma_f32_16x16x32_bf16(kf[kb], aq[ks], sreg[kb], 0, 0, 0);
    }
    __builtin_amdgcn_s_setprio(0);
#pragma unroll
    for (int kb = 0; kb < 4; kb++)
#pragma unroll
      for (int r = 0; r < 4; r++)
        lsum += __builtin_amdgcn_exp2f(sreg[kb][r] * EXPC);
    if (ct < 15) {
      *reinterpret_cast<i32x4*>(&ldsk[cur ^ 1][str * 72 + stc]) = kr0;
      *reinterpret_cast<i32x4*>(&ldsk[cur ^ 1][(str + 32) * 72 + stc]) = kr1;
      bar_lgkm();
    }
  }
  float s = lsum;
  s += __shfl_xor(s, 16);
  s += __shfl_xor(s, 32);
  const float linv = 1.f / s;

  // ---- sweep 2 prologue: stage K0 + V0 ----
  kr0 = *reinterpret_cast<const i32x4*>(&Kp[(size_t)str * HD + stc]);
  kr1 = *reinterpret_cast<const i32x4*>(&Kp[(size_t)(str + 32) * HD + stc]);
  vr0 = *reinterpret_cast<const i32x4*>(&Vp[(size_t)str * SEQ + stc]);
  vr1 = *reinterpret_cast<const i32x4*>(&Vp[(size_t)(str + 32) * SEQ + stc]);
  *reinterpret_cast<i32x4*>(&ldsk[0][str * 72 + stc]) = kr0;
  *reinterpret_cast<i32x4*>(&ldsk[0][(str + 32) * 72 + stc]) = kr1;
  *reinterpret_cast<i32x4*>(&ldsv[0][str * 72 + stc]) = vr0;
  *reinterpret_cast<i32x4*>(&ldsv[0][(str + 32) * 72 + stc]) = vr1;
  bar_lgkm();

  // ---- sweep 2: QKT -> probs -> PV -> stage-next -> ONE barrier ----
  f32x4 acc[4] = {};
  for (int ct = 0; ct < 16; ct++) {
    const int cur = ct & 1;
    if (ct < 15) {
      kr0 = *reinterpret_cast<const i32x4*>(&Kp[(size_t)((ct + 1) * 64 + str) * HD + stc]);
      kr1 = *reinterpret_cast<const i32x4*>(&Kp[(size_t)((ct + 1) * 64 + str + 32) * HD + stc]);
      vr0 = *reinterpret_cast<const i32x4*>(&Vp[(size_t)str * SEQ + (ct + 1) * 64 + stc]);
      vr1 = *reinterpret_cast<const i32x4*>(&Vp[(size_t)(str + 32) * SEQ + (ct + 1) * 64 + stc]);
    }
    f32x4 sreg[4] = {};
    __builtin_amdgcn_s_setprio(1);
#pragma unroll
    for (int ks = 0; ks < 2; ks++) {
      bf16x8 kf[4];
#pragma unroll
      for (int kb = 0; kb < 4; kb++)
        kf[kb] = *reinterpret_cast<bf16x8*>(&ldsk[cur][(kb * 16 + c) * 72 + ks * 32 + g * 8]);
#pragma unroll
      for (int kb = 0; kb < 4; kb++)
        sreg[kb] = __builtin_amdgcn_mfma_f32_16x16x32_bf16(kf[kb], aq[ks], sreg[kb], 0, 0, 0);
    }
    __builtin_amdgcn_s_setprio(0);
    {
      float* Prow = &P[(size_t)(rb + wrow + c) * SEQ + ct * 64];
#pragma unroll
      for (int kb = 0; kb < 4; kb++) {
        f32x4 p;
#pragma unroll
        for (int r = 0; r < 4; r++)
          p[r] = __builtin_amdgcn_exp2f(sreg[kb][r] * EXPC) * linv;
        *reinterpret_cast<f32x4*>(&Prow[kb * 16 + g * 4]) = p;
        uint2 pk;
        pk.x = (unsigned)f2b(p[0]) | ((unsigned)f2b(p[1]) << 16);
        pk.y = (unsigned)f2b(p[2]) | ((unsigned)f2b(p[3]) << 16);
        *reinterpret_cast<uint2*>(&lp[(wrow + c) * 72 + kb * 16 + g * 4]) = pk;
      }
    }
    __builtin_amdgcn_s_setprio(1);
#pragma unroll
    for (int ks = 0; ks < 2; ks++) {
      bf16x8 pa, vf[4];
      pa = *reinterpret_cast<bf16x8*>(&lp[(wrow + c) * 72 + ks * 32 + g * 8]);
#pragma unroll
      for (int db = 0; db < 4; db++)
        vf[db] = *reinterpret_cast<bf16x8*>(&ldsv[cur][(db * 16 + c) * 72 + ks * 32 + g * 8]);
#pragma unroll
      for (int db = 0; db < 4; db++)
        acc[db] = __builtin_amdgcn_mfma_f32_16x16x32_bf16(pa, vf[db], acc[db], 0, 0, 0);
    }
    __builtin_amdgcn_s_setprio(0);
    if (ct < 15) {
      *reinterpret_cast<i32x4*>(&ldsk[cur ^ 1][str * 72 + stc]) = kr0;
      *reinterpret_cast<i32x4*>(&ldsk[cur ^ 1][(str + 32) * 72 + stc]) = kr1;
      *reinterpret_cast<i32x4*>(&ldsv[cur ^ 1][str * 72 + stc]) = vr0;
      *reinterpret_cast<i32x4*>(&ldsv[cur ^ 1][(str + 32) * 72 + stc]) = vr1;
      bar_lgkm();
    }
  }

  // ---- CTX epilogue ----
  bar_lgkm();
#pragma unroll
  for (int db = 0; db < 4; db++)
#pragma unroll
    for (int r = 0; r < 4; r++)
      lp[(wrow + g * 4 + r) * 72 + db * 16 + c] = f2b(acc[db][r]);
  bar_lgkm();
  {
    const int q = tid >> 2, seg = (tid & 3) * 16;
    const unsigned short* src = &lp[q * 72 + seg];
    unsigned short* dst = &CTX[(size_t)(b * SEQ + rb + q) * HIDV + h * HD + seg];
    i32x4 t0 = *reinterpret_cast<const i32x4*>(&src[0]);
    i32x4 t1 = *reinterpret_cast<const i32x4*>(&src[8]);
    *reinterpret_cast<i32x4*>(&dst[0]) = t0;
    *reinterpret_cast<i32x4*>(&dst[8]) = t1;
  }
}

// ---------- output projection: 64x128 tile (384 blocks), T3-min pipeline ----------
__global__ __launch_bounds__(256) void proj_gemm(
    const unsigned short* __restrict__ Ab, const unsigned short* __restrict__ Wb,
    const float* __restrict__ bias, float* __restrict__ out) {
  __shared__ __align__(16) unsigned short la[2][64 * 32];
  __shared__ __align__(16) unsigned short lb[2][128 * 32];
  const int m0 = blockIdx.x * 64, n0 = blockIdx.y * 128;
  const int tid = threadIdx.x;
  const int wave = tid >> 6, lane = tid & 63, g = lane >> 4, c = lane & 15;
  const int wr = (wave >> 1) * 32, wc = (wave & 1) * 64;
  const int srb = wave * 16 + (lane >> 2);
  const int scol = (lane & 3) * 8;
  const unsigned short* Ag = &Ab[(size_t)(m0 + srb) * HIDV + scol];
  const unsigned short* Bg = &Wb[(size_t)(n0 + srb) * HIDV + scol];

#define PROJ_STAGE(buf, kt)                                               \
  do {                                                                    \
    gl16(Ag + (kt), &la[buf][(wave * 16) * 32]);                          \
    gl16(Bg + (kt), &lb[buf][(wave * 16) * 32]);                          \
    gl16(Bg + (size_t)64 * HIDV + (kt), &lb[buf][(64 + wave * 16) * 32]); \
  } while (0)

  PROJ_STAGE(0, 0);
  __syncthreads();

  f32x4 acc[2][4] = {};
  for (int t = 0; t < 24; t++) {
    const int cur = t & 1;
    if (t < 23) PROJ_STAGE(cur ^ 1, (t + 1) * 32);
    bf16x8 af[2], bfr[4];
#pragma unroll
    for (int m = 0; m < 2; m++)
      af[m] = *reinterpret_cast<bf16x8*>(&la[cur][(wr + m * 16 + c) * 32 + g * 8]);
#pragma unroll
    for (int n = 0; n < 4; n++)
      bfr[n] = *reinterpret_cast<bf16x8*>(&lb[cur][(wc + n * 16 + c) * 32 + g * 8]);
#pragma unroll
    for (int m = 0; m < 2; m++)
#pragma unroll
      for (int n = 0; n < 4; n++)
        acc[m][n] = __builtin_amdgcn_mfma_f32_16x16x32_bf16(af[m], bfr[n], acc[m][n], 0, 0, 0);
    __syncthreads();
  }
#undef PROJ_STAGE
  float bv4[4];
#pragma unroll
  for (int n = 0; n < 4; n++) bv4[n] = bias[n0 + wc + n * 16 + c];
#pragma unroll
  for (int m = 0; m < 2; m++) {
    int rb_ = m0 + wr + m * 16 + g * 4;
#pragma unroll
    for (int n = 0; n < 4; n++) {
      int col = n0 + wc + n * 16 + c;
#pragma unroll
      for (int r = 0; r < 4; r++)
        out[(size_t)(rb_ + r) * HIDV + col] = acc[m][n][r] + bv4[n];
    }
  }
}

extern "C" void kernel_launch(void* const* d_in, const int* in_sizes, int n_in,
                              void* d_out, int out_size, void* d_ws, size_t ws_size,
                              hipStream_t stream) {
  const float* X  = (const float*)d_in[0];
  const float* Wq = (const float*)d_in[1];
  const float* bq = (const float*)d_in[2];
  const float* Wk = (const float*)d_in[3];
  const float* bk = (const float*)d_in[4];
  const float* Wv = (const float*)d_in[5];
  const float* bv = (const float*)d_in[6];
  const float* Wo = (const float*)d_in[7];
  const float* bo = (const float*)d_in[8];
  float* out = (float*)d_out;
  float* probs = out + 3145728;  // output 1 region

  unsigned short* Xb  = (unsigned short*)d_ws;        // [4096,768]
  unsigned short* Wqb = Xb + 3145728;                 // [768,768]
  unsigned short* Wkb = Wqb + 589824;
  unsigned short* Wvb = Wkb + 589824;
  unsigned short* Wob = Wvb + 589824;
  unsigned short* Qh  = Wob + 589824;                 // [4,12,1024,64]
  unsigned short* Kh  = Qh + 3145728;
  unsigned short* VT  = Kh + 3145728;                 // [4,12,64,1024]
  unsigned short* CTX = VT + 3145728;                 // [4096,768]

  convert_all<<<5376, 256, 0, stream>>>(X, Wq, Wk, Wv, Wo, Xb);
  qkv_gemm<<<dim3(32, 6, 3), 256, 0, stream>>>(Xb, Wqb, Wkb, Wvb, bq, bk, bv, Qh, Kh, VT);
  attn_fused<<<dim3(768), 256, 0, stream>>>(Qh, Kh, VT, probs, CTX);
  proj_gemm<<<dim3(64, 6), 256, 0, stream>>>(CTX, Wob, bo, out);
}